// Round 7
// baseline (761.277 us; speedup 1.0000x reference)
//
#include <hip/hip_runtime.h>
#include <hip/hip_bf16.h>
#include <stdint.h>

#define HDIM 128

typedef __attribute__((ext_vector_type(8))) short short8;
typedef __attribute__((ext_vector_type(4))) float f32x4;

__device__ __forceinline__ ushort f2bf(float f) {
  uint u = __float_as_uint(f);
  u = (u + 0x7fffu + ((u >> 16) & 1u)) >> 16;
  return (ushort)u;
}
__device__ __forceinline__ float bflo(uint v) { return __uint_as_float(v << 16); }
__device__ __forceinline__ float bfhi(uint v) { return __uint_as_float(v & 0xffff0000u); }

// ---------------- setup kernels ----------------

// Phase A: pure edge stream -> 8 dst-range buckets. No degree atomics (those
// are counted XCD-locally in count_local). Wave-ballot ranking, one line-padded
// allocator counter per bucket. Entry packed: d_local (14b) | src<<14 (17b).
__global__ __launch_bounds__(256) void bucket_edges(const int* __restrict__ ei,
                                                    int* __restrict__ bktcur,
                                                    uint* __restrict__ bkt, int E,
                                                    int N, float inv8, int cap) {
  const int lane = threadIdx.x & 63;
  const int wavei = blockIdx.x * 4 + (threadIdx.x >> 6);
  const int base_idx = wavei * 256;  // 256 edges per wave
  if (base_idx >= E) return;
  const unsigned long long lt = (1ull << lane) - 1ull;

  int bs[4], rk[4], pf[4];
  uint pk[4];
  int tot[8];
#pragma unroll
  for (int k = 0; k < 8; ++k) tot[k] = 0;

#pragma unroll
  for (int j = 0; j < 4; ++j) {
    int idx = base_idx + j * 64 + lane;
    bool valid = idx < E;
    int b = 8;
    if (valid) {
      int s = ei[idx];
      int d = ei[E + idx];
      b = (int)((float)d * inv8);
      int n0b = (b * N) >> 3;
      if (d < n0b) {
        --b;
        n0b = (b * N) >> 3;
      } else {
        int n1b = ((b + 1) * N) >> 3;
        if (d >= n1b) {
          ++b;
          n0b = n1b;
        }
      }
      pk[j] = (uint)(d - n0b) | ((uint)s << 14);
    }
    int rank = 0, prefix = 0;
#pragma unroll
    for (int k = 0; k < 8; ++k) {
      unsigned long long m = __ballot(b == k);
      int c = __popcll(m);
      if (b == k) {
        rank = __popcll(m & lt);
        prefix = tot[k];
      }
      tot[k] += c;
    }
    bs[j] = b;
    rk[j] = rank;
    pf[j] = prefix;
  }

  int myTot = 0;
#pragma unroll
  for (int k = 0; k < 8; ++k)
    if (lane == k) myTot = tot[k];
  int mybase = 0;
  if (lane < 8 && myTot > 0) mybase = atomicAdd(&bktcur[lane * 16], myTot);
#pragma unroll
  for (int j = 0; j < 4; ++j) {
    if (bs[j] < 8) {
      int bb = __shfl(mybase, bs[j], 64);
      __builtin_nontemporal_store(
          pk[j], &bkt[(size_t)bs[j] * cap + bb + pf[j] + rk[j]]);
    }
  }
}

// Degree count, XCD-local: blocks %8==g read bucket g; cnt atomics confined to
// that bucket's 50KB node range (single-XCD L2 lines, merged evictions).
__global__ __launch_bounds__(256) void count_local(const uint* __restrict__ bkt,
                                                   const int* __restrict__ bktcur,
                                                   int* __restrict__ cnt, int cap,
                                                   int N) {
  const int g = blockIdx.x & 7;
  const int nb = gridDim.x >> 3;
  const int bi = blockIdx.x >> 3;
  const int ecnt = bktcur[g * 16];
  const int n0 = (g * N) >> 3;
  const uint* eb = bkt + (size_t)g * cap;
  for (int i = bi * 256 + threadIdx.x; i < ecnt; i += nb * 256) {
    uint u = __builtin_nontemporal_load(eb + i);
    atomicAdd(&cnt[n0 + (int)(u & 0x3FFFu)], 1);
  }
}

__global__ __launch_bounds__(256) void dis_kernel(const int* __restrict__ cnt,
                                                  float* __restrict__ dis, int N) {
  int i = blockIdx.x * 256 + threadIdx.x;
  if (i < N) dis[i] = rsqrtf((float)(cnt[i] + 1));  // +1 self loop, deg>=1 always
}

// padded degree: deg = cnt+1 padded to multiple of 4
__device__ __forceinline__ int pdeg4(int c) { return (c + 4) & ~3; }

__global__ __launch_bounds__(256) void scan1(const int* __restrict__ cnt,
                                             int* __restrict__ bsum, int N) {
  __shared__ int red[256];
  int b = blockIdx.x, t = threadIdx.x;
  int base = b * 1024;
  int s = 0;
  for (int i = t; i < 1024; i += 256) {
    int n = base + i;
    if (n < N) s += pdeg4(cnt[n]);
  }
  red[t] = s;
  __syncthreads();
  for (int off = 128; off; off >>= 1) {
    if (t < off) red[t] += red[t + off];
    __syncthreads();
  }
  if (t == 0) bsum[b] = red[0];
}

__global__ __launch_bounds__(256) void scan2(int* __restrict__ bsum, int nb) {
  __shared__ int sh[256];
  int t = threadIdx.x;
  int v = (t < nb) ? bsum[t] : 0;
  sh[t] = v;
  __syncthreads();
  for (int off = 1; off < 256; off <<= 1) {
    int add = (t >= off) ? sh[t - off] : 0;
    __syncthreads();
    sh[t] += add;
    __syncthreads();
  }
  if (t < nb) bsum[t] = sh[t] - v;
}

__global__ __launch_bounds__(256) void scan3(const int* __restrict__ cnt,
                                             const int* __restrict__ bsum,
                                             int* __restrict__ rowptr,
                                             int* __restrict__ cursor, int N) {
  __shared__ int sh[256];
  int b = blockIdx.x, t = threadIdx.x;
  int base = b * 1024 + t * 4;
  int v[4];
#pragma unroll
  for (int i = 0; i < 4; ++i) {
    int n = base + i;
    v[i] = (n < N) ? pdeg4(cnt[n]) : 0;
  }
  int tsum = v[0] + v[1] + v[2] + v[3];
  sh[t] = tsum;
  __syncthreads();
  for (int off = 1; off < 256; off <<= 1) {
    int add = (t >= off) ? sh[t - off] : 0;
    __syncthreads();
    sh[t] += add;
    __syncthreads();
  }
  int p = sh[t] - tsum + bsum[b];
#pragma unroll
  for (int i = 0; i < 4; ++i) {
    int n = base + i;
    if (n <= N) rowptr[n] = p;
    if (n < N) cursor[n] = p;
    p += v[i];
  }
}

// packed entry: src (17 bits) | bf15 weight << 17 (weight in (0,1], sign dropped)
__device__ __forceinline__ uint pack_cw(int src, float w) {
  uint w15 = (__float_as_uint(w) + 0x8000u) >> 16;  // 15 bits (w <= 1.0)
  return (uint)src | (w15 << 17);
}
__device__ __forceinline__ uint cw_src(uint u) { return u & 0x1FFFFu; }
__device__ __forceinline__ float cw_w(uint u) { return __uint_as_float((u >> 17) << 16); }

// Phase B: bucket g handled only by blocks with blockIdx&7==g (XCD-local cursor
// atomics + colw scatter -> full merged line evictions). Self-loops folded in
// over the bucket's node range.
__global__ __launch_bounds__(256) void fill_csr2(const uint* __restrict__ bkt,
                                                 const int* __restrict__ bktcur,
                                                 const float* __restrict__ dis,
                                                 int* __restrict__ cursor,
                                                 uint* __restrict__ colw, int cap,
                                                 int N) {
  const int g = blockIdx.x & 7;
  const int nb = gridDim.x >> 3;
  const int bi = blockIdx.x >> 3;
  const int ecnt = bktcur[g * 16];
  const int n0 = (g * N) >> 3;
  const uint* eb = bkt + (size_t)g * cap;
  for (int i = bi * 256 + threadIdx.x; i < ecnt; i += nb * 256) {
    uint u = __builtin_nontemporal_load(eb + i);
    int d = n0 + (int)(u & 0x3FFFu);
    int s = (int)(u >> 14);
    int pos = atomicAdd(&cursor[d], 1);
    colw[pos] = pack_cw(s, dis[s] * dis[d]);
  }
  const int n1 = ((g + 1) * N) >> 3;
  for (int n = n0 + bi * 256 + threadIdx.x; n < n1; n += nb * 256) {
    int pos = atomicAdd(&cursor[n], 1);
    colw[pos] = pack_cw(n, dis[n] * dis[n]);
  }
}

// zero-weight pads pointing at own row; XCD-local by node range
__global__ __launch_bounds__(256) void pad_csr2(const int* __restrict__ cnt,
                                                const int* __restrict__ rowptr,
                                                uint* __restrict__ colw, int N) {
  const int g = blockIdx.x & 7;
  const int nb = gridDim.x >> 3;
  const int bi = blockIdx.x >> 3;
  const int n0 = (g * N) >> 3, n1 = ((g + 1) * N) >> 3;
  for (int n = n0 + bi * 256 + threadIdx.x; n < n1; n += nb * 256) {
    int beg = rowptr[n] + cnt[n] + 1, end = rowptr[n + 1];
    for (int j = beg; j < end; ++j) colw[j] = (uint)n;  // src n, w 0
  }
}

// Pre-swizzle Ws into MFMA B-fragment order per layer
__global__ __launch_bounds__(256) void swz_w(const float* __restrict__ Ws,
                                             ushort* __restrict__ Wsw, int total) {
  int idx = blockIdx.x * 256 + threadIdx.x;
  if (idx >= total) return;
  int l = idx >> 14, r = idx & 16383;
  int j = r & 7, lane = (r >> 3) & 63, kk = (r >> 9) & 3, c = r >> 11;
  int n = c * 16 + (lane & 15);
  int k = kk * 32 + (lane >> 4) * 8 + j;
  Wsw[idx] = f2bf(Ws[l * 16384 + k * HDIM + n]);
}

// ---------------- per-layer kernels (row-major activations) ----------------

// XW = X @ W. Persistent: W staged in LDS once, grid-stride over 64-row tiles.
template <bool F32IN>
__global__ __launch_bounds__(256) void gemm_kernel(const void* __restrict__ Xin,
                                                   const ushort* __restrict__ Wsw,
                                                   ushort* __restrict__ XW, int N,
                                                   int ntiles) {
  __shared__ ushort wlds[16384];    // 32 KB swizzled W (persistent)
  __shared__ ushort clds[64 * 136]; // C restage, padded stride
  const int t = threadIdx.x;
  {
    const int4* src = (const int4*)Wsw;
    int4* dst = (int4*)wlds;
#pragma unroll
    for (int i = 0; i < 8; ++i) dst[t + 256 * i] = src[t + 256 * i];
  }
  __syncthreads();

  const int wave = t >> 6, lane = t & 63;
  const int kq = lane >> 4;  // 0..3

  for (int tile = blockIdx.x; tile < ntiles; tile += gridDim.x) {
    const int row0 = tile * 64 + wave * 16 + (lane & 15);
    const bool inb = row0 < N;

    short8 afr[4];
#pragma unroll
    for (int kk = 0; kk < 4; ++kk) afr[kk] = short8{0, 0, 0, 0, 0, 0, 0, 0};
    if (inb) {
      if constexpr (F32IN) {
        const float* arow = (const float*)Xin + (size_t)row0 * HDIM;
#pragma unroll
        for (int kk = 0; kk < 4; ++kk) {
          float4 x0 = *(const float4*)(arow + kk * 32 + kq * 8);
          float4 x1 = *(const float4*)(arow + kk * 32 + kq * 8 + 4);
          short8 f;
          f[0] = (short)f2bf(x0.x); f[1] = (short)f2bf(x0.y);
          f[2] = (short)f2bf(x0.z); f[3] = (short)f2bf(x0.w);
          f[4] = (short)f2bf(x1.x); f[5] = (short)f2bf(x1.y);
          f[6] = (short)f2bf(x1.z); f[7] = (short)f2bf(x1.w);
          afr[kk] = f;
        }
      } else {
        const short8* arow = (const short8*)((const ushort*)Xin + (size_t)row0 * HDIM);
#pragma unroll
        for (int kk = 0; kk < 4; ++kk) afr[kk] = arow[kk * 4 + kq];
      }
    }

    f32x4 acc[8];
#pragma unroll
    for (int c = 0; c < 8; ++c) acc[c] = f32x4{0.f, 0.f, 0.f, 0.f};
#pragma unroll
    for (int kk = 0; kk < 4; ++kk) {
#pragma unroll
      for (int c = 0; c < 8; ++c) {
        short8 bfr = *(const short8*)(wlds + (((c * 4 + kk) * 64 + lane) << 3));
        acc[c] = __builtin_amdgcn_mfma_f32_16x16x32_bf16(afr[kk], bfr, acc[c], 0, 0, 0);
      }
    }

    __syncthreads();  // previous tile's clds readers done
    const int m0 = wave * 16 + kq * 4;
#pragma unroll
    for (int c = 0; c < 8; ++c) {
      int col = c * 16 + (lane & 15);
#pragma unroll
      for (int r = 0; r < 4; ++r) clds[(m0 + r) * 136 + col] = f2bf(acc[c][r]);
    }
    __syncthreads();
    // coalesced store: 64 rows x 16 int4
#pragma unroll
    for (int i = 0; i < 4; ++i) {
      int idx = t + 256 * i;
      int row = idx >> 4, piece = idx & 15;
      int grow = tile * 64 + row;
      if (grow < N)
        ((int4*)XW)[(size_t)tile * 1024 + idx] =
            *(const int4*)(clds + row * 136 + piece * 8);
    }
  }
}

// Aggregation: one node per wave. lane = e*16+c (e: edge slot 0..3, c: 16B piece).
// 16 lanes x uint4 = full 256B row per edge; 4 edges per gather instruction.
// Burst: 6 chunks (24 edges) of colw + gathers issued back-to-back -> ~96
// line-requests in flight per wave. Chunks past pdeg clamp to last entry, w=0.
__global__ __launch_bounds__(256, 6) void agg_kernel(const ushort* __restrict__ XW,
                                                     const uint* __restrict__ colw,
                                                     const int* __restrict__ rowptr,
                                                     const float* __restrict__ bias,
                                                     ushort* __restrict__ Y, int N) {
  const int lane = threadIdx.x & 63;
  const int node = blockIdx.x * 4 + (threadIdx.x >> 6);
  if (node >= N) return;
  const int e = lane >> 4, c = lane & 15;
  const int beg = rowptr[node];
  const int pdeg = rowptr[node + 1] - beg;  // multiple of 4, >= 4
  const int last = pdeg - 1;

  uint cw[6];
#pragma unroll
  for (int k = 0; k < 6; ++k) {
    int off = 4 * k + e;
    cw[k] = __builtin_nontemporal_load(colw + beg + (off < pdeg ? off : last));
  }
  uint4 gv[6];
#pragma unroll
  for (int k = 0; k < 6; ++k)
    gv[k] = *(const uint4*)(XW + ((size_t)cw_src(cw[k]) << 7) + c * 8);

  float acc[8];
#pragma unroll
  for (int i = 0; i < 8; ++i) acc[i] = 0.f;

#pragma unroll
  for (int k = 0; k < 6; ++k) {
    int off = 4 * k + e;
    float w = (off < pdeg) ? cw_w(cw[k]) : 0.f;
    uint4 v = gv[k];
    acc[0] += w * bflo(v.x); acc[1] += w * bfhi(v.x);
    acc[2] += w * bflo(v.y); acc[3] += w * bfhi(v.y);
    acc[4] += w * bflo(v.z); acc[5] += w * bfhi(v.z);
    acc[6] += w * bflo(v.w); acc[7] += w * bfhi(v.w);
  }
  // tail for deg > 23 (rare)
  for (int off = 24 + e; off < pdeg; off += 4) {
    uint u = __builtin_nontemporal_load(colw + beg + off);
    uint4 v = *(const uint4*)(XW + ((size_t)cw_src(u) << 7) + c * 8);
    float w = cw_w(u);
    acc[0] += w * bflo(v.x); acc[1] += w * bfhi(v.x);
    acc[2] += w * bflo(v.y); acc[3] += w * bfhi(v.y);
    acc[4] += w * bflo(v.z); acc[5] += w * bfhi(v.z);
    acc[6] += w * bflo(v.w); acc[7] += w * bfhi(v.w);
  }

#pragma unroll
  for (int i = 0; i < 8; ++i) {
    acc[i] += __shfl_xor(acc[i], 16, 64);
    acc[i] += __shfl_xor(acc[i], 32, 64);
  }
  if (e == 0) {
    float4 b0 = *(const float4*)(bias + c * 8);
    float4 b1 = *(const float4*)(bias + c * 8 + 4);
    uint4 pk;
    pk.x = (uint)f2bf(fmaxf(acc[0] + b0.x, 0.f)) | ((uint)f2bf(fmaxf(acc[1] + b0.y, 0.f)) << 16);
    pk.y = (uint)f2bf(fmaxf(acc[2] + b0.z, 0.f)) | ((uint)f2bf(fmaxf(acc[3] + b0.w, 0.f)) << 16);
    pk.z = (uint)f2bf(fmaxf(acc[4] + b1.x, 0.f)) | ((uint)f2bf(fmaxf(acc[5] + b1.y, 0.f)) << 16);
    pk.w = (uint)f2bf(fmaxf(acc[6] + b1.z, 0.f)) | ((uint)f2bf(fmaxf(acc[7] + b1.w, 0.f)) << 16);
    *(uint4*)(Y + (size_t)node * HDIM + c * 8) = pk;
  }
}

// ---------------- pooling + head ----------------

__global__ __launch_bounds__(256) void pool_partial(const ushort* __restrict__ x,
                                                    const int* __restrict__ batch,
                                                    float* __restrict__ pooled,
                                                    int* __restrict__ gcnt, int N) {
  const int g = blockIdx.x, s = blockIdx.y;  // gridDim.y = 8 splits
  const int t = threadIdx.x;
  __shared__ int range[2];
  __shared__ float sums[256];
  if (t < 2) {
    int target = g + t;
    int lo = 0, hi = N;
    while (lo < hi) {
      int mid = (lo + hi) >> 1;
      if (batch[mid] < target) lo = mid + 1;
      else hi = mid;
    }
    range[t] = lo;
  }
  __syncthreads();
  int beg = range[0], end = range[1];
  if (s == 0 && t == 0) gcnt[g] = end - beg;
  int col = t & 127, half = t >> 7;
  float acc = 0.f;
  for (int n = beg + s * 2 + half; n < end; n += 16) {
    acc += __uint_as_float(((uint)x[(size_t)n * HDIM + col]) << 16);
  }
  sums[t] = acc;
  __syncthreads();
  if (t < 128) atomicAdd(&pooled[g * HDIM + t], sums[t] + sums[t + 128]);
}

__global__ __launch_bounds__(256) void out_final(const float* __restrict__ pooled,
                                                 const int* __restrict__ gcnt,
                                                 const float* __restrict__ W_out,
                                                 const float* __restrict__ b_out,
                                                 float* __restrict__ out, int G, int C) {
  int i = blockIdx.x * 256 + threadIdx.x;
  if (i >= G * C) return;
  int g = i / C, c = i - g * C;
  float inv = 1.f / (float)max(gcnt[g], 1);
  const float* pg = pooled + g * HDIM;
  float o = 0.f;
  for (int h = 0; h < HDIM; ++h) o += pg[h] * W_out[h * C + c];
  out[i] = b_out[c] + o * inv;
}

// ---------------- host ----------------

extern "C" void kernel_launch(void* const* d_in, const int* in_sizes, int n_in,
                              void* d_out, int out_size, void* d_ws, size_t ws_size,
                              hipStream_t stream) {
  (void)n_in;
  (void)ws_size;
  const float* x = (const float*)d_in[0];
  const int* ei = (const int*)d_in[1];
  const int* batch = (const int*)d_in[2];
  const float* Ws = (const float*)d_in[4];
  const float* bs = (const float*)d_in[5];
  const float* W_out = (const float*)d_in[6];
  const float* b_out = (const float*)d_in[7];
  float* out = (float*)d_out;

  const int N = in_sizes[0] / HDIM;
  const int E = in_sizes[1] / 2;
  const int L = in_sizes[5] / HDIM;
  const int C = in_sizes[7];
  const int G = out_size / C;
  const int cap = E / 4 + 1024;  // per-bucket capacity (balanced random: ~E/8)

  char* p = (char*)d_ws;
  auto carve = [&](size_t bytes) {
    char* r = p;
    p += (bytes + 255) & ~(size_t)255;
    return r;
  };
  int* cnt = (int*)carve((size_t)N * 4);
  int* bktcur = (int*)carve(512);  // 8 counters, one 64B line apart
  float* dis = (float*)carve((size_t)N * 4);
  int* rowptr = (int*)carve((size_t)(N + 1) * 4);
  int* cursor = (int*)carve((size_t)N * 4);
  int* bsum = (int*)carve(4096);
  uint* bkt = (uint*)carve((size_t)8 * cap * 4);
  uint* colw = (uint*)carve(((size_t)E + 4 * (size_t)N + 64) * 4);
  ushort* Wsw = (ushort*)carve((size_t)L * HDIM * HDIM * 2);
  ushort* xw = (ushort*)carve((size_t)N * HDIM * 2);
  ushort* y0 = (ushort*)carve((size_t)N * HDIM * 2);
  ushort* y1 = (ushort*)carve((size_t)N * HDIM * 2);
  float* pooled = (float*)carve((size_t)G * HDIM * 4 + (size_t)G * 4);
  int* gcnt = (int*)(pooled + (size_t)G * HDIM);

  hipMemsetAsync(cnt, 0, (size_t)N * 4, stream);
  hipMemsetAsync(bktcur, 0, 512, stream);
  hipMemsetAsync(pooled, 0, (size_t)G * HDIM * 4 + (size_t)G * 4, stream);

  const float inv8 = 8.0f / (float)N;
  bucket_edges<<<(E + 1023) / 1024, 256, 0, stream>>>(ei, bktcur, bkt, E, N, inv8, cap);
  count_local<<<1024, 256, 0, stream>>>(bkt, bktcur, cnt, cap, N);
  dis_kernel<<<(N + 255) / 256, 256, 0, stream>>>(cnt, dis, N);
  int nb = (N + 1 + 1023) / 1024;
  scan1<<<nb, 256, 0, stream>>>(cnt, bsum, N);
  scan2<<<1, 256, 0, stream>>>(bsum, nb);
  scan3<<<nb, 256, 0, stream>>>(cnt, bsum, rowptr, cursor, N);
  fill_csr2<<<1024, 256, 0, stream>>>(bkt, bktcur, dis, cursor, colw, cap, N);
  pad_csr2<<<1024, 256, 0, stream>>>(cnt, rowptr, colw, N);
  swz_w<<<(L * HDIM * HDIM + 255) / 256, 256, 0, stream>>>(Ws, Wsw, L * HDIM * HDIM);

  const int ntiles = (N + 63) / 64;
  const int gb = 768;  // persistent: 3 blocks/CU (49.4 KB LDS)
  gemm_kernel<true><<<gb, 256, 0, stream>>>(x, Wsw, xw, N, ntiles);
  agg_kernel<<<(N + 3) / 4, 256, 0, stream>>>(xw, colw, rowptr, bs, y0, N);
  ushort* xc = y0;
  ushort* xn = y1;
  for (int l = 1; l < L; ++l) {
    gemm_kernel<false><<<gb, 256, 0, stream>>>(xc, Wsw + (size_t)l * HDIM * HDIM, xw, N, ntiles);
    agg_kernel<<<(N + 3) / 4, 256, 0, stream>>>(xw, colw, rowptr, bs + (size_t)l * HDIM, xn, N);
    ushort* tmp = xc;
    xc = xn;
    xn = tmp;
  }
  pool_partial<<<dim3(G, 8), 256, 0, stream>>>(xc, batch, pooled, gcnt, N);
  out_final<<<(G * C + 255) / 256, 256, 0, stream>>>(pooled, gcnt, W_out, b_out, out, G, C);
}

// Round 8
// 653.983 us; speedup vs baseline: 1.1641x; 1.1641x over previous
//
#include <hip/hip_runtime.h>
#include <hip/hip_bf16.h>
#include <stdint.h>

#define HDIM 128

typedef __attribute__((ext_vector_type(8))) short short8;
typedef __attribute__((ext_vector_type(4))) float f32x4;

__device__ __forceinline__ ushort f2bf(float f) {
  uint u = __float_as_uint(f);
  u = (u + 0x7fffu + ((u >> 16) & 1u)) >> 16;
  return (ushort)u;
}
__device__ __forceinline__ float bflo(uint v) { return __uint_as_float(v << 16); }
__device__ __forceinline__ float bfhi(uint v) { return __uint_as_float(v & 0xffff0000u); }

// ---------------- setup kernels ----------------

// Phase A: pure edge stream -> 8 dst-range buckets. No degree atomics (counted
// XCD-locally in count_local). LDS-hist ranking + ONE allocator atomic per
// bucket per block (~12.5k total, no hot-line serialization). Entry packed:
// d_local (14b) | src<<14 (17b). Scatter lands in ~1KB contiguous per-bucket
// runs -> full-line L2 merges.
__global__ __launch_bounds__(256) void bucket_edges(const int* __restrict__ ei,
                                                    int* __restrict__ bktcur,
                                                    uint* __restrict__ bkt, int E,
                                                    int N, float inv8, int cap) {
  __shared__ int hist[8], base[8];
  const int t = threadIdx.x;
  const int c0 = blockIdx.x * 2048;
  if (t < 8) hist[t] = 0;
  __syncthreads();
  uint pk[8];
  int bidx[8], rk[8];
#pragma unroll
  for (int j = 0; j < 8; ++j) {
    int idx = c0 + j * 256 + t;
    bidx[j] = -1;
    if (idx < E) {
      int s = ei[idx];
      int d = ei[E + idx];
      int b = (int)((float)d * inv8);
      int n0b = (b * N) >> 3;
      if (d < n0b) {
        --b;
        n0b = (b * N) >> 3;
      } else {
        int n1b = ((b + 1) * N) >> 3;
        if (d >= n1b) {
          ++b;
          n0b = n1b;
        }
      }
      pk[j] = (uint)(d - n0b) | ((uint)s << 14);
      bidx[j] = b;
      rk[j] = atomicAdd(&hist[b], 1);
    }
  }
  __syncthreads();
  if (t < 8) base[t] = atomicAdd(&bktcur[t * 16], hist[t]);
  __syncthreads();
#pragma unroll
  for (int j = 0; j < 8; ++j) {
    if (bidx[j] >= 0)
      __builtin_nontemporal_store(
          pk[j], &bkt[(size_t)bidx[j] * cap + base[bidx[j]] + rk[j]]);
  }
}

// Degree count, XCD-local: blocks %8==g read bucket g; cnt atomics confined to
// that bucket's 50KB node range (single-XCD L2 lines, merged evictions).
__global__ __launch_bounds__(256) void count_local(const uint* __restrict__ bkt,
                                                   const int* __restrict__ bktcur,
                                                   int* __restrict__ cnt, int cap,
                                                   int N) {
  const int g = blockIdx.x & 7;
  const int nb = gridDim.x >> 3;
  const int bi = blockIdx.x >> 3;
  const int ecnt = bktcur[g * 16];
  const int n0 = (g * N) >> 3;
  const uint* eb = bkt + (size_t)g * cap;
  for (int i = bi * 256 + threadIdx.x; i < ecnt; i += nb * 256) {
    uint u = __builtin_nontemporal_load(eb + i);
    atomicAdd(&cnt[n0 + (int)(u & 0x3FFFu)], 1);
  }
}

__global__ __launch_bounds__(256) void dis_kernel(const int* __restrict__ cnt,
                                                  float* __restrict__ dis, int N) {
  int i = blockIdx.x * 256 + threadIdx.x;
  if (i < N) dis[i] = rsqrtf((float)(cnt[i] + 1));  // +1 self loop, deg>=1 always
}

// padded degree: deg = cnt+1 padded to multiple of 4
__device__ __forceinline__ int pdeg4(int c) { return (c + 4) & ~3; }

__global__ __launch_bounds__(256) void scan1(const int* __restrict__ cnt,
                                             int* __restrict__ bsum, int N) {
  __shared__ int red[256];
  int b = blockIdx.x, t = threadIdx.x;
  int base = b * 1024;
  int s = 0;
  for (int i = t; i < 1024; i += 256) {
    int n = base + i;
    if (n < N) s += pdeg4(cnt[n]);
  }
  red[t] = s;
  __syncthreads();
  for (int off = 128; off; off >>= 1) {
    if (t < off) red[t] += red[t + off];
    __syncthreads();
  }
  if (t == 0) bsum[b] = red[0];
}

__global__ __launch_bounds__(256) void scan2(int* __restrict__ bsum, int nb) {
  __shared__ int sh[256];
  int t = threadIdx.x;
  int v = (t < nb) ? bsum[t] : 0;
  sh[t] = v;
  __syncthreads();
  for (int off = 1; off < 256; off <<= 1) {
    int add = (t >= off) ? sh[t - off] : 0;
    __syncthreads();
    sh[t] += add;
    __syncthreads();
  }
  if (t < nb) bsum[t] = sh[t] - v;
}

__global__ __launch_bounds__(256) void scan3(const int* __restrict__ cnt,
                                             const int* __restrict__ bsum,
                                             int* __restrict__ rowptr,
                                             int* __restrict__ cursor, int N) {
  __shared__ int sh[256];
  int b = blockIdx.x, t = threadIdx.x;
  int base = b * 1024 + t * 4;
  int v[4];
#pragma unroll
  for (int i = 0; i < 4; ++i) {
    int n = base + i;
    v[i] = (n < N) ? pdeg4(cnt[n]) : 0;
  }
  int tsum = v[0] + v[1] + v[2] + v[3];
  sh[t] = tsum;
  __syncthreads();
  for (int off = 1; off < 256; off <<= 1) {
    int add = (t >= off) ? sh[t - off] : 0;
    __syncthreads();
    sh[t] += add;
    __syncthreads();
  }
  int p = sh[t] - tsum + bsum[b];
#pragma unroll
  for (int i = 0; i < 4; ++i) {
    int n = base + i;
    if (n <= N) rowptr[n] = p;
    if (n < N) cursor[n] = p;
    p += v[i];
  }
}

// packed entry: src (17 bits) | bf15 weight << 17 (weight in (0,1], sign dropped)
__device__ __forceinline__ uint pack_cw(int src, float w) {
  uint w15 = (__float_as_uint(w) + 0x8000u) >> 16;  // 15 bits (w <= 1.0)
  return (uint)src | (w15 << 17);
}
__device__ __forceinline__ uint cw_src(uint u) { return u & 0x1FFFFu; }
__device__ __forceinline__ float cw_w(uint u) { return __uint_as_float((u >> 17) << 16); }

// Phase B: bucket g handled only by blocks with blockIdx&7==g (XCD-local cursor
// atomics + colw scatter -> full merged line evictions). Self-loops folded in
// over the bucket's node range.
__global__ __launch_bounds__(256) void fill_csr2(const uint* __restrict__ bkt,
                                                 const int* __restrict__ bktcur,
                                                 const float* __restrict__ dis,
                                                 int* __restrict__ cursor,
                                                 uint* __restrict__ colw, int cap,
                                                 int N) {
  const int g = blockIdx.x & 7;
  const int nb = gridDim.x >> 3;
  const int bi = blockIdx.x >> 3;
  const int ecnt = bktcur[g * 16];
  const int n0 = (g * N) >> 3;
  const uint* eb = bkt + (size_t)g * cap;
  for (int i = bi * 256 + threadIdx.x; i < ecnt; i += nb * 256) {
    uint u = __builtin_nontemporal_load(eb + i);
    int d = n0 + (int)(u & 0x3FFFu);
    int s = (int)(u >> 14);
    int pos = atomicAdd(&cursor[d], 1);
    colw[pos] = pack_cw(s, dis[s] * dis[d]);
  }
  const int n1 = ((g + 1) * N) >> 3;
  for (int n = n0 + bi * 256 + threadIdx.x; n < n1; n += nb * 256) {
    int pos = atomicAdd(&cursor[n], 1);
    colw[pos] = pack_cw(n, dis[n] * dis[n]);
  }
}

// zero-weight pads pointing at own row; XCD-local by node range
__global__ __launch_bounds__(256) void pad_csr2(const int* __restrict__ cnt,
                                                const int* __restrict__ rowptr,
                                                uint* __restrict__ colw, int N) {
  const int g = blockIdx.x & 7;
  const int nb = gridDim.x >> 3;
  const int bi = blockIdx.x >> 3;
  const int n0 = (g * N) >> 3, n1 = ((g + 1) * N) >> 3;
  for (int n = n0 + bi * 256 + threadIdx.x; n < n1; n += nb * 256) {
    int beg = rowptr[n] + cnt[n] + 1, end = rowptr[n + 1];
    for (int j = beg; j < end; ++j) colw[j] = (uint)n;  // src n, w 0
  }
}

// Pre-swizzle Ws into MFMA B-fragment order per layer
__global__ __launch_bounds__(256) void swz_w(const float* __restrict__ Ws,
                                             ushort* __restrict__ Wsw, int total) {
  int idx = blockIdx.x * 256 + threadIdx.x;
  if (idx >= total) return;
  int l = idx >> 14, r = idx & 16383;
  int j = r & 7, lane = (r >> 3) & 63, kk = (r >> 9) & 3, c = r >> 11;
  int n = c * 16 + (lane & 15);
  int k = kk * 32 + (lane >> 4) * 8 + j;
  Wsw[idx] = f2bf(Ws[l * 16384 + k * HDIM + n]);
}

// ---------------- per-layer kernels (row-major activations) ----------------

// XW = X @ W. Persistent: W staged in LDS once, grid-stride over 64-row tiles.
template <bool F32IN>
__global__ __launch_bounds__(256) void gemm_kernel(const void* __restrict__ Xin,
                                                   const ushort* __restrict__ Wsw,
                                                   ushort* __restrict__ XW, int N,
                                                   int ntiles) {
  __shared__ ushort wlds[16384];    // 32 KB swizzled W (persistent)
  __shared__ ushort clds[64 * 136]; // C restage, padded stride
  const int t = threadIdx.x;
  {
    const int4* src = (const int4*)Wsw;
    int4* dst = (int4*)wlds;
#pragma unroll
    for (int i = 0; i < 8; ++i) dst[t + 256 * i] = src[t + 256 * i];
  }
  __syncthreads();

  const int wave = t >> 6, lane = t & 63;
  const int kq = lane >> 4;  // 0..3

  for (int tile = blockIdx.x; tile < ntiles; tile += gridDim.x) {
    const int row0 = tile * 64 + wave * 16 + (lane & 15);
    const bool inb = row0 < N;

    short8 afr[4];
#pragma unroll
    for (int kk = 0; kk < 4; ++kk) afr[kk] = short8{0, 0, 0, 0, 0, 0, 0, 0};
    if (inb) {
      if constexpr (F32IN) {
        const float* arow = (const float*)Xin + (size_t)row0 * HDIM;
#pragma unroll
        for (int kk = 0; kk < 4; ++kk) {
          float4 x0 = *(const float4*)(arow + kk * 32 + kq * 8);
          float4 x1 = *(const float4*)(arow + kk * 32 + kq * 8 + 4);
          short8 f;
          f[0] = (short)f2bf(x0.x); f[1] = (short)f2bf(x0.y);
          f[2] = (short)f2bf(x0.z); f[3] = (short)f2bf(x0.w);
          f[4] = (short)f2bf(x1.x); f[5] = (short)f2bf(x1.y);
          f[6] = (short)f2bf(x1.z); f[7] = (short)f2bf(x1.w);
          afr[kk] = f;
        }
      } else {
        const short8* arow = (const short8*)((const ushort*)Xin + (size_t)row0 * HDIM);
#pragma unroll
        for (int kk = 0; kk < 4; ++kk) afr[kk] = arow[kk * 4 + kq];
      }
    }

    f32x4 acc[8];
#pragma unroll
    for (int c = 0; c < 8; ++c) acc[c] = f32x4{0.f, 0.f, 0.f, 0.f};
#pragma unroll
    for (int kk = 0; kk < 4; ++kk) {
#pragma unroll
      for (int c = 0; c < 8; ++c) {
        short8 bfr = *(const short8*)(wlds + (((c * 4 + kk) * 64 + lane) << 3));
        acc[c] = __builtin_amdgcn_mfma_f32_16x16x32_bf16(afr[kk], bfr, acc[c], 0, 0, 0);
      }
    }

    __syncthreads();  // previous tile's clds readers done
    const int m0 = wave * 16 + kq * 4;
#pragma unroll
    for (int c = 0; c < 8; ++c) {
      int col = c * 16 + (lane & 15);
#pragma unroll
      for (int r = 0; r < 4; ++r) clds[(m0 + r) * 136 + col] = f2bf(acc[c][r]);
    }
    __syncthreads();
    // coalesced store: 64 rows x 16 int4
#pragma unroll
    for (int i = 0; i < 4; ++i) {
      int idx = t + 256 * i;
      int row = idx >> 4, piece = idx & 15;
      int grow = tile * 64 + row;
      if (grow < N)
        ((int4*)XW)[(size_t)tile * 1024 + idx] =
            *(const int4*)(clds + row * 136 + piece * 8);
    }
  }
}

// Aggregation: one node per wave. lane = e*16+c (e: edge slot 0..3, c: 16B piece).
// 16 lanes x uint4 = full 256B row per edge; 4 edges per gather instruction.
// Burst: 6 chunks (24 edges) of colw + gathers issued back-to-back -> ~96
// line-requests in flight per wave. Chunks past pdeg clamp to last entry, w=0.
__global__ __launch_bounds__(256, 6) void agg_kernel(const ushort* __restrict__ XW,
                                                     const uint* __restrict__ colw,
                                                     const int* __restrict__ rowptr,
                                                     const float* __restrict__ bias,
                                                     ushort* __restrict__ Y, int N) {
  const int lane = threadIdx.x & 63;
  const int node = blockIdx.x * 4 + (threadIdx.x >> 6);
  if (node >= N) return;
  const int e = lane >> 4, c = lane & 15;
  const int beg = rowptr[node];
  const int pdeg = rowptr[node + 1] - beg;  // multiple of 4, >= 4
  const int last = pdeg - 1;

  uint cw[6];
#pragma unroll
  for (int k = 0; k < 6; ++k) {
    int off = 4 * k + e;
    cw[k] = __builtin_nontemporal_load(colw + beg + (off < pdeg ? off : last));
  }
  uint4 gv[6];
#pragma unroll
  for (int k = 0; k < 6; ++k)
    gv[k] = *(const uint4*)(XW + ((size_t)cw_src(cw[k]) << 7) + c * 8);

  float acc[8];
#pragma unroll
  for (int i = 0; i < 8; ++i) acc[i] = 0.f;

#pragma unroll
  for (int k = 0; k < 6; ++k) {
    int off = 4 * k + e;
    float w = (off < pdeg) ? cw_w(cw[k]) : 0.f;
    uint4 v = gv[k];
    acc[0] += w * bflo(v.x); acc[1] += w * bfhi(v.x);
    acc[2] += w * bflo(v.y); acc[3] += w * bfhi(v.y);
    acc[4] += w * bflo(v.z); acc[5] += w * bfhi(v.z);
    acc[6] += w * bflo(v.w); acc[7] += w * bfhi(v.w);
  }
  // tail for deg > 23 (rare)
  for (int off = 24 + e; off < pdeg; off += 4) {
    uint u = __builtin_nontemporal_load(colw + beg + off);
    uint4 v = *(const uint4*)(XW + ((size_t)cw_src(u) << 7) + c * 8);
    float w = cw_w(u);
    acc[0] += w * bflo(v.x); acc[1] += w * bfhi(v.x);
    acc[2] += w * bflo(v.y); acc[3] += w * bfhi(v.y);
    acc[4] += w * bflo(v.z); acc[5] += w * bfhi(v.z);
    acc[6] += w * bflo(v.w); acc[7] += w * bfhi(v.w);
  }

#pragma unroll
  for (int i = 0; i < 8; ++i) {
    acc[i] += __shfl_xor(acc[i], 16, 64);
    acc[i] += __shfl_xor(acc[i], 32, 64);
  }
  if (e == 0) {
    float4 b0 = *(const float4*)(bias + c * 8);
    float4 b1 = *(const float4*)(bias + c * 8 + 4);
    uint4 pk;
    pk.x = (uint)f2bf(fmaxf(acc[0] + b0.x, 0.f)) | ((uint)f2bf(fmaxf(acc[1] + b0.y, 0.f)) << 16);
    pk.y = (uint)f2bf(fmaxf(acc[2] + b0.z, 0.f)) | ((uint)f2bf(fmaxf(acc[3] + b0.w, 0.f)) << 16);
    pk.z = (uint)f2bf(fmaxf(acc[4] + b1.x, 0.f)) | ((uint)f2bf(fmaxf(acc[5] + b1.y, 0.f)) << 16);
    pk.w = (uint)f2bf(fmaxf(acc[6] + b1.z, 0.f)) | ((uint)f2bf(fmaxf(acc[7] + b1.w, 0.f)) << 16);
    *(uint4*)(Y + (size_t)node * HDIM + c * 8) = pk;
  }
}

// ---------------- pooling + head ----------------

__global__ __launch_bounds__(256) void pool_partial(const ushort* __restrict__ x,
                                                    const int* __restrict__ batch,
                                                    float* __restrict__ pooled,
                                                    int* __restrict__ gcnt, int N) {
  const int g = blockIdx.x, s = blockIdx.y;  // gridDim.y = 8 splits
  const int t = threadIdx.x;
  __shared__ int range[2];
  __shared__ float sums[256];
  if (t < 2) {
    int target = g + t;
    int lo = 0, hi = N;
    while (lo < hi) {
      int mid = (lo + hi) >> 1;
      if (batch[mid] < target) lo = mid + 1;
      else hi = mid;
    }
    range[t] = lo;
  }
  __syncthreads();
  int beg = range[0], end = range[1];
  if (s == 0 && t == 0) gcnt[g] = end - beg;
  int col = t & 127, half = t >> 7;
  float acc = 0.f;
  for (int n = beg + s * 2 + half; n < end; n += 16) {
    acc += __uint_as_float(((uint)x[(size_t)n * HDIM + col]) << 16);
  }
  sums[t] = acc;
  __syncthreads();
  if (t < 128) atomicAdd(&pooled[g * HDIM + t], sums[t] + sums[t + 128]);
}

__global__ __launch_bounds__(256) void out_final(const float* __restrict__ pooled,
                                                 const int* __restrict__ gcnt,
                                                 const float* __restrict__ W_out,
                                                 const float* __restrict__ b_out,
                                                 float* __restrict__ out, int G, int C) {
  int i = blockIdx.x * 256 + threadIdx.x;
  if (i >= G * C) return;
  int g = i / C, c = i - g * C;
  float inv = 1.f / (float)max(gcnt[g], 1);
  const float* pg = pooled + g * HDIM;
  float o = 0.f;
  for (int h = 0; h < HDIM; ++h) o += pg[h] * W_out[h * C + c];
  out[i] = b_out[c] + o * inv;
}

// ---------------- host ----------------

extern "C" void kernel_launch(void* const* d_in, const int* in_sizes, int n_in,
                              void* d_out, int out_size, void* d_ws, size_t ws_size,
                              hipStream_t stream) {
  (void)n_in;
  (void)ws_size;
  const float* x = (const float*)d_in[0];
  const int* ei = (const int*)d_in[1];
  const int* batch = (const int*)d_in[2];
  const float* Ws = (const float*)d_in[4];
  const float* bs = (const float*)d_in[5];
  const float* W_out = (const float*)d_in[6];
  const float* b_out = (const float*)d_in[7];
  float* out = (float*)d_out;

  const int N = in_sizes[0] / HDIM;
  const int E = in_sizes[1] / 2;
  const int L = in_sizes[5] / HDIM;
  const int C = in_sizes[7];
  const int G = out_size / C;
  const int cap = E / 4 + 1024;  // per-bucket capacity (balanced random: ~E/8)

  char* p = (char*)d_ws;
  auto carve = [&](size_t bytes) {
    char* r = p;
    p += (bytes + 255) & ~(size_t)255;
    return r;
  };
  int* cnt = (int*)carve((size_t)N * 4);
  int* bktcur = (int*)carve(512);  // 8 counters, one 64B line apart
  float* dis = (float*)carve((size_t)N * 4);
  int* rowptr = (int*)carve((size_t)(N + 1) * 4);
  int* cursor = (int*)carve((size_t)N * 4);
  int* bsum = (int*)carve(4096);
  uint* bkt = (uint*)carve((size_t)8 * cap * 4);
  uint* colw = (uint*)carve(((size_t)E + 4 * (size_t)N + 64) * 4);
  ushort* Wsw = (ushort*)carve((size_t)L * HDIM * HDIM * 2);
  ushort* xw = (ushort*)carve((size_t)N * HDIM * 2);
  ushort* y0 = (ushort*)carve((size_t)N * HDIM * 2);
  ushort* y1 = (ushort*)carve((size_t)N * HDIM * 2);
  float* pooled = (float*)carve((size_t)G * HDIM * 4 + (size_t)G * 4);
  int* gcnt = (int*)(pooled + (size_t)G * HDIM);

  hipMemsetAsync(cnt, 0, (size_t)N * 4, stream);
  hipMemsetAsync(bktcur, 0, 512, stream);
  hipMemsetAsync(pooled, 0, (size_t)G * HDIM * 4 + (size_t)G * 4, stream);

  const float inv8 = 8.0f / (float)N;
  bucket_edges<<<(E + 2047) / 2048, 256, 0, stream>>>(ei, bktcur, bkt, E, N, inv8, cap);
  count_local<<<1024, 256, 0, stream>>>(bkt, bktcur, cnt, cap, N);
  dis_kernel<<<(N + 255) / 256, 256, 0, stream>>>(cnt, dis, N);
  int nb = (N + 1 + 1023) / 1024;
  scan1<<<nb, 256, 0, stream>>>(cnt, bsum, N);
  scan2<<<1, 256, 0, stream>>>(bsum, nb);
  scan3<<<nb, 256, 0, stream>>>(cnt, bsum, rowptr, cursor, N);
  fill_csr2<<<1024, 256, 0, stream>>>(bkt, bktcur, dis, cursor, colw, cap, N);
  pad_csr2<<<1024, 256, 0, stream>>>(cnt, rowptr, colw, N);
  swz_w<<<(L * HDIM * HDIM + 255) / 256, 256, 0, stream>>>(Ws, Wsw, L * HDIM * HDIM);

  const int ntiles = (N + 63) / 64;
  const int gb = 768;  // persistent: 3 blocks/CU (49.4 KB LDS)
  gemm_kernel<true><<<gb, 256, 0, stream>>>(x, Wsw, xw, N, ntiles);
  agg_kernel<<<(N + 3) / 4, 256, 0, stream>>>(xw, colw, rowptr, bs, y0, N);
  ushort* xc = y0;
  ushort* xn = y1;
  for (int l = 1; l < L; ++l) {
    gemm_kernel<false><<<gb, 256, 0, stream>>>(xc, Wsw + (size_t)l * HDIM * HDIM, xw, N, ntiles);
    agg_kernel<<<(N + 3) / 4, 256, 0, stream>>>(xw, colw, rowptr, bs + (size_t)l * HDIM, xn, N);
    ushort* tmp = xc;
    xc = xn;
    xn = tmp;
  }
  pool_partial<<<dim3(G, 8), 256, 0, stream>>>(xc, batch, pooled, gcnt, N);
  out_final<<<(G * C + 255) / 256, 256, 0, stream>>>(pooled, gcnt, W_out, b_out, out, G, C);
}

// Round 9
// 573.487 us; speedup vs baseline: 1.3275x; 1.1404x over previous
//
#include <hip/hip_runtime.h>
#include <hip/hip_bf16.h>
#include <stdint.h>

#define HDIM 128
#define SBITS 10
#define SBMAX 128  // supports N <= 131072

typedef __attribute__((ext_vector_type(8))) short short8;
typedef __attribute__((ext_vector_type(4))) float f32x4;

__device__ __forceinline__ ushort f2bf(float f) {
  uint u = __float_as_uint(f);
  u = (u + 0x7fffu + ((u >> 16) & 1u)) >> 16;
  return (ushort)u;
}
__device__ __forceinline__ float bflo(uint v) { return __uint_as_float(v << 16); }
__device__ __forceinline__ float bfhi(uint v) { return __uint_as_float(v & 0xffff0000u); }

// padded degree: deg = cnt+1 padded to multiple of 4
__device__ __forceinline__ int pdeg4(int c) { return (c + 4) & ~3; }

// packed colw entry: src (17 bits) | bf15 weight << 17 (weight in (0,1])
__device__ __forceinline__ uint pack_cw(int src, float w) {
  uint w15 = (__float_as_uint(w) + 0x8000u) >> 16;
  return (uint)src | (w15 << 17);
}
__device__ __forceinline__ uint cw_src(uint u) { return u & 0x1FFFFu; }
__device__ __forceinline__ float cw_w(uint u) { return __uint_as_float((u >> 17) << 16); }

// ---------------- setup: CSR build with zero global RMW hotspots ----------------

// Edge stream -> SB sub-buckets of 1024 dst nodes. Entry: d_local(10b)|src<<10.
// LDS-hist ranking; ONE allocator atomic per sub-bucket per block. Plain stores
// (append runs ~21 entries merge in L2; no nontemporal eviction).
__global__ __launch_bounds__(256) void bucket_edges(const int* __restrict__ ei,
                                                    int* __restrict__ bktcur,
                                                    uint* __restrict__ bkt, int E,
                                                    int cap) {
  __shared__ int hist[SBMAX], base[SBMAX];
  const int t = threadIdx.x;
  const int c0 = blockIdx.x * 2048;
  for (int i = t; i < SBMAX; i += 256) hist[i] = 0;
  __syncthreads();
  uint pk[8];
  int sb_[8], rk[8];
#pragma unroll
  for (int j = 0; j < 8; ++j) {
    int idx = c0 + j * 256 + t;
    sb_[j] = -1;
    if (idx < E) {
      int s = ei[idx];
      int d = ei[E + idx];
      int b = d >> SBITS;
      pk[j] = (uint)(d & 1023) | ((uint)s << SBITS);
      sb_[j] = b;
      rk[j] = atomicAdd(&hist[b], 1);
    }
  }
  __syncthreads();
  for (int i = t; i < SBMAX; i += 256)
    base[i] = hist[i] ? atomicAdd(&bktcur[i * 16], hist[i]) : 0;
  __syncthreads();
#pragma unroll
  for (int j = 0; j < 8; ++j)
    if (sb_[j] >= 0)
      bkt[(size_t)sb_[j] * cap + base[sb_[j]] + rk[j]] = pk[j];
}

// One block owns one sub-bucket: LDS count -> dis + padded-degree total.
__global__ __launch_bounds__(256) void csr_count(const uint* __restrict__ bkt,
                                                 const int* __restrict__ bktcur,
                                                 float* __restrict__ dis,
                                                 int* __restrict__ sbtot, int cap,
                                                 int N) {
  __shared__ int cnt[1024];
  __shared__ int red[256];
  const int sb = blockIdx.x, t = threadIdx.x;
  const int n0 = sb << SBITS;
  const int ecnt = bktcur[sb * 16];
  const uint* eb = bkt + (size_t)sb * cap;
  for (int i = t; i < 1024; i += 256) cnt[i] = 0;
  __syncthreads();
  for (int i = t; i < ecnt; i += 256)
    atomicAdd(&cnt[__builtin_nontemporal_load(eb + i) & 1023], 1);
  __syncthreads();
  int s = 0;
#pragma unroll
  for (int j = 0; j < 4; ++j) {
    int idx = t * 4 + j, n = n0 + idx;
    if (n < N) {
      dis[n] = rsqrtf((float)(cnt[idx] + 1));
      s += pdeg4(cnt[idx]);
    }
  }
  red[t] = s;
  __syncthreads();
  for (int off = 128; off; off >>= 1) {
    if (t < off) red[t] += red[t + off];
    __syncthreads();
  }
  if (t == 0) sbtot[sb] = red[0];
}

// Exclusive scan of SB sub-bucket totals (SB <= 128); also writes rowptr[N].
__global__ __launch_bounds__(128) void scan_sb(const int* __restrict__ sbtot,
                                               int* __restrict__ sbbase,
                                               int* __restrict__ rowptr, int SB,
                                               int N) {
  __shared__ int sh[128];
  int t = threadIdx.x;
  int v = (t < SB) ? sbtot[t] : 0;
  sh[t] = v;
  __syncthreads();
  for (int off = 1; off < 128; off <<= 1) {
    int add = (t >= off) ? sh[t - off] : 0;
    __syncthreads();
    sh[t] += add;
    __syncthreads();
  }
  if (t < SB) sbbase[t] = sh[t] - v;
  if (t == 127) rowptr[N] = sh[127];
}

// One block owns one sub-bucket: recount, LDS prefix, write rowptr (coalesced),
// place self-loop/pads/edges via LDS cursors. Its 86KB colw range is written by
// exactly one CU -> full-line merged evictions; NO global atomics.
__global__ __launch_bounds__(256) void csr_place(const uint* __restrict__ bkt,
                                                 const int* __restrict__ bktcur,
                                                 const int* __restrict__ sbbase,
                                                 const float* __restrict__ dis,
                                                 int* __restrict__ rowptr,
                                                 uint* __restrict__ colw, int cap,
                                                 int N) {
  __shared__ int cnt[1024], cur[1024];
  __shared__ int sh[256];
  const int sb = blockIdx.x, t = threadIdx.x;
  const int n0 = sb << SBITS;
  const int ecnt = bktcur[sb * 16];
  const uint* eb = bkt + (size_t)sb * cap;
  const int base = sbbase[sb];
  for (int i = t; i < 1024; i += 256) cnt[i] = 0;
  __syncthreads();
  for (int i = t; i < ecnt; i += 256)
    atomicAdd(&cnt[__builtin_nontemporal_load(eb + i) & 1023], 1);
  __syncthreads();
  int v[4], tsum = 0;
#pragma unroll
  for (int j = 0; j < 4; ++j) {
    int idx = t * 4 + j, n = n0 + idx;
    v[j] = (n < N) ? pdeg4(cnt[idx]) : 0;
    tsum += v[j];
  }
  sh[t] = tsum;
  __syncthreads();
  for (int off = 1; off < 256; off <<= 1) {
    int add = (t >= off) ? sh[t - off] : 0;
    __syncthreads();
    sh[t] += add;
    __syncthreads();
  }
  int p = sh[t] - tsum;
#pragma unroll
  for (int j = 0; j < 4; ++j) {
    int idx = t * 4 + j, n = n0 + idx;
    if (n < N) {
      rowptr[n] = base + p;
      cur[idx] = p + 1;  // self-loop occupies slot p
      float dn = dis[n];
      colw[base + p] = pack_cw(n, dn * dn);
      int deg = cnt[idx];
      for (int q = deg + 1; q < v[j]; ++q) colw[base + p + q] = (uint)n;  // pads
    }
    p += v[j];
  }
  __syncthreads();
  for (int i = t; i < ecnt; i += 256) {
    uint u = __builtin_nontemporal_load(eb + i);
    int dloc = (int)(u & 1023);
    int s2 = (int)(u >> SBITS);
    int pos = atomicAdd(&cur[dloc], 1);  // LDS cursor
    int d = n0 + dloc;
    colw[base + pos] = pack_cw(s2, dis[s2] * dis[d]);
  }
}

// Pre-swizzle Ws into MFMA B-fragment order per layer
__global__ __launch_bounds__(256) void swz_w(const float* __restrict__ Ws,
                                             ushort* __restrict__ Wsw, int total) {
  int idx = blockIdx.x * 256 + threadIdx.x;
  if (idx >= total) return;
  int l = idx >> 14, r = idx & 16383;
  int j = r & 7, lane = (r >> 3) & 63, kk = (r >> 9) & 3, c = r >> 11;
  int n = c * 16 + (lane & 15);
  int k = kk * 32 + (lane >> 4) * 8 + j;
  Wsw[idx] = f2bf(Ws[l * 16384 + k * HDIM + n]);
}

// ---------------- per-layer kernels (row-major activations) ----------------

// XW = X @ W. Persistent: W staged in LDS once, grid-stride over 64-row tiles.
template <bool F32IN>
__global__ __launch_bounds__(256) void gemm_kernel(const void* __restrict__ Xin,
                                                   const ushort* __restrict__ Wsw,
                                                   ushort* __restrict__ XW, int N,
                                                   int ntiles) {
  __shared__ ushort wlds[16384];    // 32 KB swizzled W (persistent)
  __shared__ ushort clds[64 * 136]; // C restage, padded stride
  const int t = threadIdx.x;
  {
    const int4* src = (const int4*)Wsw;
    int4* dst = (int4*)wlds;
#pragma unroll
    for (int i = 0; i < 8; ++i) dst[t + 256 * i] = src[t + 256 * i];
  }
  __syncthreads();

  const int wave = t >> 6, lane = t & 63;
  const int kq = lane >> 4;  // 0..3

  for (int tile = blockIdx.x; tile < ntiles; tile += gridDim.x) {
    const int row0 = tile * 64 + wave * 16 + (lane & 15);
    const bool inb = row0 < N;

    short8 afr[4];
#pragma unroll
    for (int kk = 0; kk < 4; ++kk) afr[kk] = short8{0, 0, 0, 0, 0, 0, 0, 0};
    if (inb) {
      if constexpr (F32IN) {
        const float* arow = (const float*)Xin + (size_t)row0 * HDIM;
#pragma unroll
        for (int kk = 0; kk < 4; ++kk) {
          float4 x0 = *(const float4*)(arow + kk * 32 + kq * 8);
          float4 x1 = *(const float4*)(arow + kk * 32 + kq * 8 + 4);
          short8 f;
          f[0] = (short)f2bf(x0.x); f[1] = (short)f2bf(x0.y);
          f[2] = (short)f2bf(x0.z); f[3] = (short)f2bf(x0.w);
          f[4] = (short)f2bf(x1.x); f[5] = (short)f2bf(x1.y);
          f[6] = (short)f2bf(x1.z); f[7] = (short)f2bf(x1.w);
          afr[kk] = f;
        }
      } else {
        const short8* arow = (const short8*)((const ushort*)Xin + (size_t)row0 * HDIM);
#pragma unroll
        for (int kk = 0; kk < 4; ++kk) afr[kk] = arow[kk * 4 + kq];
      }
    }

    f32x4 acc[8];
#pragma unroll
    for (int c = 0; c < 8; ++c) acc[c] = f32x4{0.f, 0.f, 0.f, 0.f};
#pragma unroll
    for (int kk = 0; kk < 4; ++kk) {
#pragma unroll
      for (int c = 0; c < 8; ++c) {
        short8 bfr = *(const short8*)(wlds + (((c * 4 + kk) * 64 + lane) << 3));
        acc[c] = __builtin_amdgcn_mfma_f32_16x16x32_bf16(afr[kk], bfr, acc[c], 0, 0, 0);
      }
    }

    __syncthreads();  // previous tile's clds readers done
    const int m0 = wave * 16 + kq * 4;
#pragma unroll
    for (int c = 0; c < 8; ++c) {
      int col = c * 16 + (lane & 15);
#pragma unroll
      for (int r = 0; r < 4; ++r) clds[(m0 + r) * 136 + col] = f2bf(acc[c][r]);
    }
    __syncthreads();
    // coalesced store: 64 rows x 16 int4
#pragma unroll
    for (int i = 0; i < 4; ++i) {
      int idx = t + 256 * i;
      int row = idx >> 4, piece = idx & 15;
      int grow = tile * 64 + row;
      if (grow < N)
        ((int4*)XW)[(size_t)tile * 1024 + idx] =
            *(const int4*)(clds + row * 136 + piece * 8);
    }
  }
}

// Aggregation: one node per wave. lane = e*16+c; 16 lanes x uint4 = full 256B
// row per edge, 4 edges per gather instruction, 24 edges in flight per wave.
__global__ __launch_bounds__(256, 6) void agg_kernel(const ushort* __restrict__ XW,
                                                     const uint* __restrict__ colw,
                                                     const int* __restrict__ rowptr,
                                                     const float* __restrict__ bias,
                                                     ushort* __restrict__ Y, int N) {
  const int lane = threadIdx.x & 63;
  const int node = blockIdx.x * 4 + (threadIdx.x >> 6);
  if (node >= N) return;
  const int e = lane >> 4, c = lane & 15;
  const int beg = rowptr[node];
  const int pdeg = rowptr[node + 1] - beg;  // multiple of 4, >= 4
  const int last = pdeg - 1;

  uint cw[6];
#pragma unroll
  for (int k = 0; k < 6; ++k) {
    int off = 4 * k + e;
    cw[k] = __builtin_nontemporal_load(colw + beg + (off < pdeg ? off : last));
  }
  uint4 gv[6];
#pragma unroll
  for (int k = 0; k < 6; ++k)
    gv[k] = *(const uint4*)(XW + ((size_t)cw_src(cw[k]) << 7) + c * 8);

  float acc[8];
#pragma unroll
  for (int i = 0; i < 8; ++i) acc[i] = 0.f;

#pragma unroll
  for (int k = 0; k < 6; ++k) {
    int off = 4 * k + e;
    float w = (off < pdeg) ? cw_w(cw[k]) : 0.f;
    uint4 v = gv[k];
    acc[0] += w * bflo(v.x); acc[1] += w * bfhi(v.x);
    acc[2] += w * bflo(v.y); acc[3] += w * bfhi(v.y);
    acc[4] += w * bflo(v.z); acc[5] += w * bfhi(v.z);
    acc[6] += w * bflo(v.w); acc[7] += w * bfhi(v.w);
  }
  // tail for deg > 23 (rare)
  for (int off = 24 + e; off < pdeg; off += 4) {
    uint u = __builtin_nontemporal_load(colw + beg + off);
    uint4 v = *(const uint4*)(XW + ((size_t)cw_src(u) << 7) + c * 8);
    float w = cw_w(u);
    acc[0] += w * bflo(v.x); acc[1] += w * bfhi(v.x);
    acc[2] += w * bflo(v.y); acc[3] += w * bfhi(v.y);
    acc[4] += w * bflo(v.z); acc[5] += w * bfhi(v.z);
    acc[6] += w * bflo(v.w); acc[7] += w * bfhi(v.w);
  }

#pragma unroll
  for (int i = 0; i < 8; ++i) {
    acc[i] += __shfl_xor(acc[i], 16, 64);
    acc[i] += __shfl_xor(acc[i], 32, 64);
  }
  if (e == 0) {
    float4 b0 = *(const float4*)(bias + c * 8);
    float4 b1 = *(const float4*)(bias + c * 8 + 4);
    uint4 pk;
    pk.x = (uint)f2bf(fmaxf(acc[0] + b0.x, 0.f)) | ((uint)f2bf(fmaxf(acc[1] + b0.y, 0.f)) << 16);
    pk.y = (uint)f2bf(fmaxf(acc[2] + b0.z, 0.f)) | ((uint)f2bf(fmaxf(acc[3] + b0.w, 0.f)) << 16);
    pk.z = (uint)f2bf(fmaxf(acc[4] + b1.x, 0.f)) | ((uint)f2bf(fmaxf(acc[5] + b1.y, 0.f)) << 16);
    pk.w = (uint)f2bf(fmaxf(acc[6] + b1.z, 0.f)) | ((uint)f2bf(fmaxf(acc[7] + b1.w, 0.f)) << 16);
    *(uint4*)(Y + (size_t)node * HDIM + c * 8) = pk;
  }
}

// ---------------- pooling + head ----------------

__global__ __launch_bounds__(256) void pool_partial(const ushort* __restrict__ x,
                                                    const int* __restrict__ batch,
                                                    float* __restrict__ pooled,
                                                    int* __restrict__ gcnt, int N) {
  const int g = blockIdx.x, s = blockIdx.y;  // gridDim.y = 8 splits
  const int t = threadIdx.x;
  __shared__ int range[2];
  __shared__ float sums[256];
  if (t < 2) {
    int target = g + t;
    int lo = 0, hi = N;
    while (lo < hi) {
      int mid = (lo + hi) >> 1;
      if (batch[mid] < target) lo = mid + 1;
      else hi = mid;
    }
    range[t] = lo;
  }
  __syncthreads();
  int beg = range[0], end = range[1];
  if (s == 0 && t == 0) gcnt[g] = end - beg;
  int col = t & 127, half = t >> 7;
  float acc = 0.f;
  for (int n = beg + s * 2 + half; n < end; n += 16) {
    acc += __uint_as_float(((uint)x[(size_t)n * HDIM + col]) << 16);
  }
  sums[t] = acc;
  __syncthreads();
  if (t < 128) atomicAdd(&pooled[g * HDIM + t], sums[t] + sums[t + 128]);
}

__global__ __launch_bounds__(256) void out_final(const float* __restrict__ pooled,
                                                 const int* __restrict__ gcnt,
                                                 const float* __restrict__ W_out,
                                                 const float* __restrict__ b_out,
                                                 float* __restrict__ out, int G, int C) {
  int i = blockIdx.x * 256 + threadIdx.x;
  if (i >= G * C) return;
  int g = i / C, c = i - g * C;
  float inv = 1.f / (float)max(gcnt[g], 1);
  const float* pg = pooled + g * HDIM;
  float o = 0.f;
  for (int h = 0; h < HDIM; ++h) o += pg[h] * W_out[h * C + c];
  out[i] = b_out[c] + o * inv;
}

// ---------------- host ----------------

extern "C" void kernel_launch(void* const* d_in, const int* in_sizes, int n_in,
                              void* d_out, int out_size, void* d_ws, size_t ws_size,
                              hipStream_t stream) {
  (void)n_in;
  (void)ws_size;
  const float* x = (const float*)d_in[0];
  const int* ei = (const int*)d_in[1];
  const int* batch = (const int*)d_in[2];
  const float* Ws = (const float*)d_in[4];
  const float* bs = (const float*)d_in[5];
  const float* W_out = (const float*)d_in[6];
  const float* b_out = (const float*)d_in[7];
  float* out = (float*)d_out;

  const int N = in_sizes[0] / HDIM;
  const int E = in_sizes[1] / 2;
  const int L = in_sizes[5] / HDIM;
  const int C = in_sizes[7];
  const int G = out_size / C;
  const int SB = (N + 1023) >> SBITS;        // sub-buckets of 1024 nodes
  const int cap = E / SB + 8192;             // per-sub-bucket capacity

  char* p = (char*)d_ws;
  auto carve = [&](size_t bytes) {
    char* r = p;
    p += (bytes + 255) & ~(size_t)255;
    return r;
  };
  int* bktcur = (int*)carve(SBMAX * 64);     // one 64B line per counter
  float* dis = (float*)carve((size_t)N * 4);
  int* rowptr = (int*)carve((size_t)(N + 1) * 4);
  int* sbtot = (int*)carve(SBMAX * 4);
  int* sbbase = (int*)carve(SBMAX * 4);
  uint* bkt = (uint*)carve((size_t)SB * cap * 4);
  uint* colw = (uint*)carve(((size_t)E + 4 * (size_t)N + 64) * 4);
  ushort* Wsw = (ushort*)carve((size_t)L * HDIM * HDIM * 2);
  ushort* xw = (ushort*)carve((size_t)N * HDIM * 2);
  ushort* y0 = (ushort*)carve((size_t)N * HDIM * 2);
  ushort* y1 = (ushort*)carve((size_t)N * HDIM * 2);
  float* pooled = (float*)carve((size_t)G * HDIM * 4 + (size_t)G * 4);
  int* gcnt = (int*)(pooled + (size_t)G * HDIM);

  hipMemsetAsync(bktcur, 0, SBMAX * 64, stream);
  hipMemsetAsync(pooled, 0, (size_t)G * HDIM * 4 + (size_t)G * 4, stream);

  bucket_edges<<<(E + 2047) / 2048, 256, 0, stream>>>(ei, bktcur, bkt, E, cap);
  csr_count<<<SB, 256, 0, stream>>>(bkt, bktcur, dis, sbtot, cap, N);
  scan_sb<<<1, 128, 0, stream>>>(sbtot, sbbase, rowptr, SB, N);
  csr_place<<<SB, 256, 0, stream>>>(bkt, bktcur, sbbase, dis, rowptr, colw, cap, N);
  swz_w<<<(L * HDIM * HDIM + 255) / 256, 256, 0, stream>>>(Ws, Wsw, L * HDIM * HDIM);

  const int ntiles = (N + 63) / 64;
  const int gb = 768;  // persistent: 3 blocks/CU (49.4 KB LDS)
  gemm_kernel<true><<<gb, 256, 0, stream>>>(x, Wsw, xw, N, ntiles);
  agg_kernel<<<(N + 3) / 4, 256, 0, stream>>>(xw, colw, rowptr, bs, y0, N);
  ushort* xc = y0;
  ushort* xn = y1;
  for (int l = 1; l < L; ++l) {
    gemm_kernel<false><<<gb, 256, 0, stream>>>(xc, Wsw + (size_t)l * HDIM * HDIM, xw, N, ntiles);
    agg_kernel<<<(N + 3) / 4, 256, 0, stream>>>(xw, colw, rowptr, bs + (size_t)l * HDIM, xn, N);
    ushort* tmp = xc;
    xc = xn;
    xn = tmp;
  }
  pool_partial<<<dim3(G, 8), 256, 0, stream>>>(xc, batch, pooled, gcnt, N);
  out_final<<<(G * C + 255) / 256, 256, 0, stream>>>(pooled, gcnt, W_out, b_out, out, G, C);
}